// Round 2
// baseline (4426.339 us; speedup 1.0000x reference)
//
#include <hip/hip_runtime.h>

using short8 = __attribute__((ext_vector_type(8))) short;
using sh4    = __attribute__((ext_vector_type(4))) short;
using f32x4  = __attribute__((ext_vector_type(4))) float;

#define DEVI static __device__ __forceinline__

DEVI unsigned short f2bf(float f) {
  union { float f; unsigned u; } v; v.f = f;
  unsigned r = v.u + 0x7FFFu + ((v.u >> 16) & 1u);
  return (unsigned short)(r >> 16);
}
DEVI float bf2f(unsigned short h) {
  union { unsigned u; float f; } v; v.u = (unsigned)h << 16;
  return v.f;
}
DEVI void splitf(float f, unsigned short& hi, unsigned short& lo) {
  unsigned short h = f2bf(f);
  hi = h;
  lo = f2bf(f - bf2f(h));
}

static constexpr int  B_  = 64;
static constexpr int  S_  = 512;
static constexpr int  IN_ = 512;
static constexpr int  NB_ = 64;    // n_blk
static constexpr int  DH_ = 1024;  // d_hid
static constexpr long M_  = (long)B_ * S_;  // 32768 rows

// ---------------------------------------------------------------------------
// prep: split-transpose all weights to bf16 hi/lo pairs [n][k]; init h buffer.
// ---------------------------------------------------------------------------
__global__ void prep_kernel(const float* __restrict__ Wmc, const float* __restrict__ Wig,
                            const float* __restrict__ Wog,
                            const float* __restrict__ Umc, const float* __restrict__ Uig,
                            const float* __restrict__ Uog,
                            const float* __restrict__ h0,
                            unsigned short* __restrict__ WmcTh, unsigned short* __restrict__ WmcTl,
                            unsigned short* __restrict__ WigTh, unsigned short* __restrict__ WigTl,
                            unsigned short* __restrict__ WogTh, unsigned short* __restrict__ WogTl,
                            unsigned short* __restrict__ UmcTh, unsigned short* __restrict__ UmcTl,
                            unsigned short* __restrict__ UigTh, unsigned short* __restrict__ UigTl,
                            unsigned short* __restrict__ UogTh, unsigned short* __restrict__ UogTl,
                            unsigned short* __restrict__ hbh,   unsigned short* __restrict__ hbl)
{
  const long e0 = 1024L * 512;        // WmcT
  const long e1 = e0 + 64L * 512;     // WigT
  const long e2 = e1 + 64L * 512;     // WogT
  const long e3 = e2 + 1024L * 1024;  // UmcT
  const long e4 = e3 + 64L * 1024;    // UigT
  const long e5 = e4 + 64L * 1024;    // UogT
  const long e6 = e5 + 64L * 1024;    // hbuf
  for (long i = (long)blockIdx.x * blockDim.x + threadIdx.x; i < e6;
       i += (long)gridDim.x * blockDim.x) {
    float v; unsigned short *ph, *pl; long idx;
    if (i < e0) {
      idx = i; long n = idx >> 9, k = idx & 511;
      v = Wmc[k * 1024 + n]; ph = WmcTh; pl = WmcTl;
    } else if (i < e1) {
      idx = i - e0; long n = idx >> 9, k = idx & 511;
      v = Wig[k * 64 + n]; ph = WigTh; pl = WigTl;
    } else if (i < e2) {
      idx = i - e1; long n = idx >> 9, k = idx & 511;
      v = Wog[k * 64 + n]; ph = WogTh; pl = WogTl;
    } else if (i < e3) {
      idx = i - e2; long n = idx >> 10, k = idx & 1023;
      v = Umc[k * 1024 + n]; ph = UmcTh; pl = UmcTl;
    } else if (i < e4) {
      idx = i - e3; long n = idx >> 10, k = idx & 1023;
      v = Uig[k * 64 + n]; ph = UigTh; pl = UigTl;
    } else if (i < e5) {
      idx = i - e4; long n = idx >> 10, k = idx & 1023;
      v = Uog[k * 64 + n]; ph = UogTh; pl = UogTl;
    } else {
      idx = i - e5;
      v = h0[idx & 1023]; ph = hbh; pl = hbl;
    }
    unsigned short hi, lo; splitf(v, hi, lo);
    ph[idx] = hi; pl[idx] = lo;
  }
}

// ---------------------------------------------------------------------------
// Split-precision GEMM: C(MxN f32) = A(MxK f32) @ BT(NxK bf16 hi/lo)^T + bias.
// A is split to hi/lo bf16 in registers during LDS staging.
// K=512. Block tile 128x64, BK=64, 4 waves 2x2 (wave tile 64x32).
// C ~= Ah@Bh + Al@Bh + Ah@Bl  (f32 MFMA accumulate).
// ---------------------------------------------------------------------------
__global__ __launch_bounds__(256) void gemm_split(
    const float* __restrict__ A,
    const unsigned short* __restrict__ BTh,
    const unsigned short* __restrict__ BTl,
    const float* __restrict__ bias,
    float* __restrict__ C,
    int N)
{
  const int K = 512;
  __shared__ unsigned short Ah[128][72];
  __shared__ unsigned short Alo[128][72];
  __shared__ unsigned short Bh[64][72];
  __shared__ unsigned short Blo[64][72];
  int tid = threadIdx.x, lane = tid & 63, w = tid >> 6;
  int wm = w & 1, wn = w >> 1;
  int m0 = blockIdx.x * 128, n0 = blockIdx.y * 64;
  f32x4 acc[4][2] = {};
  for (int kt = 0; kt < K; kt += 64) {
    __syncthreads();
#pragma unroll
    for (int i = 0; i < 8; ++i) {  // A tile: 128 rows x 64 cols (f32 -> split)
      int c = tid + i * 256; int r = c >> 4, o = (c & 15) * 4;
      float4 v = *(const float4*)&A[(long)(m0 + r) * K + kt + o];
      sh4 hi, lo;
      { unsigned short h_, l_;
        splitf(v.x, h_, l_); hi[0] = (short)h_; lo[0] = (short)l_;
        splitf(v.y, h_, l_); hi[1] = (short)h_; lo[1] = (short)l_;
        splitf(v.z, h_, l_); hi[2] = (short)h_; lo[2] = (short)l_;
        splitf(v.w, h_, l_); hi[3] = (short)h_; lo[3] = (short)l_; }
      *(sh4*)&Ah[r][o]  = hi;
      *(sh4*)&Alo[r][o] = lo;
    }
#pragma unroll
    for (int i = 0; i < 2; ++i) {  // B tiles: 64 n-rows x 64 k-cols
      int c = tid + i * 256; int r = c >> 3, o = (c & 7) * 8;
      *(short8*)&Bh[r][o]  = *(const short8*)&BTh[(long)(n0 + r) * K + kt + o];
      *(short8*)&Blo[r][o] = *(const short8*)&BTl[(long)(n0 + r) * K + kt + o];
    }
    __syncthreads();
#pragma unroll
    for (int ks = 0; ks < 2; ++ks) {
      short8 ah[4], al[4], bh[2], bl[2];
      int kk = ks * 32 + (lane >> 4) * 8;
#pragma unroll
      for (int mt = 0; mt < 4; ++mt) {
        ah[mt] = *(const short8*)&Ah[wm * 64 + mt * 16 + (lane & 15)][kk];
        al[mt] = *(const short8*)&Alo[wm * 64 + mt * 16 + (lane & 15)][kk];
      }
#pragma unroll
      for (int nt = 0; nt < 2; ++nt) {
        bh[nt] = *(const short8*)&Bh[wn * 32 + nt * 16 + (lane & 15)][kk];
        bl[nt] = *(const short8*)&Blo[wn * 32 + nt * 16 + (lane & 15)][kk];
      }
#pragma unroll
      for (int mt = 0; mt < 4; ++mt)
#pragma unroll
        for (int nt = 0; nt < 2; ++nt) {
          acc[mt][nt] = __builtin_amdgcn_mfma_f32_16x16x32_bf16(
              ah[mt], bl[nt], acc[mt][nt], 0, 0, 0);
          acc[mt][nt] = __builtin_amdgcn_mfma_f32_16x16x32_bf16(
              al[mt], bh[nt], acc[mt][nt], 0, 0, 0);
          acc[mt][nt] = __builtin_amdgcn_mfma_f32_16x16x32_bf16(
              ah[mt], bh[nt], acc[mt][nt], 0, 0, 0);
        }
    }
  }
#pragma unroll
  for (int mt = 0; mt < 4; ++mt)
#pragma unroll
    for (int nt = 0; nt < 2; ++nt) {
      int col = n0 + wn * 32 + nt * 16 + (lane & 15);
      float bv = bias[col];
#pragma unroll
      for (int r = 0; r < 4; ++r) {
        int row = m0 + wm * 64 + mt * 16 + (lane >> 4) * 4 + r;
        C[(long)row * N + col] = acc[mt][nt][r] + bv;
      }
    }
}

// ---------------------------------------------------------------------------
// One recurrent step, split precision. grid=(64 blk-strips, 4 b-groups),
// 256 threads (4 waves, K split 256 each). acc0: 16 Umc cols; acc1: gate
// cols [Uig_blk | Uog_blk | junk]. 3 MFMAs per operand pair (~f32 exact).
// xmc staged in hseq and overwritten with h in-place.
// ---------------------------------------------------------------------------
__global__ __launch_bounds__(256) void lstm_step(
    const unsigned short* __restrict__ hih, const unsigned short* __restrict__ hil,
    unsigned short* __restrict__ hoh,       unsigned short* __restrict__ hol,
    const unsigned short* __restrict__ UmcTh, const unsigned short* __restrict__ UmcTl,
    const unsigned short* __restrict__ UigTh, const unsigned short* __restrict__ UigTl,
    const unsigned short* __restrict__ UogTh, const unsigned short* __restrict__ UogTl,
    const float* __restrict__ xig,            // 32768 x 64
    const float* __restrict__ xog,            // 32768 x 64
    const float* __restrict__ c0,             // 1024
    float* __restrict__ hseq,                 // d_out h region (xmc staged)
    float* __restrict__ cseq,                 // d_out c region
    int t)
{
  int tid = threadIdx.x, lane = tid & 63, w = tid >> 6;
  int blk = blockIdx.x, mg = blockIdx.y;
  __shared__ float pA[4][16][16];
  __shared__ float pG[4][16][16];
  f32x4 acc0 = {}, acc1 = {};
  bool isog = ((lane & 15) == 1);
  const unsigned short* g_h = (isog ? UogTh : UigTh) + (long)blk * DH_;
  const unsigned short* g_l = (isog ? UogTl : UigTl) + (long)blk * DH_;
  long arow = (long)(mg * 16 + (lane & 15)) * DH_;
  long brow = (long)(blk * 16 + (lane & 15)) * DH_;
#pragma unroll
  for (int k8 = 0; k8 < 8; ++k8) {
    int kk = w * 256 + k8 * 32 + (lane >> 4) * 8;
    short8 ah = *(const short8*)&hih[arow + kk];
    short8 al = *(const short8*)&hil[arow + kk];
    short8 b0h = *(const short8*)&UmcTh[brow + kk];
    short8 b0l = *(const short8*)&UmcTl[brow + kk];
    short8 b1h = *(const short8*)&g_h[kk];
    short8 b1l = *(const short8*)&g_l[kk];
    acc0 = __builtin_amdgcn_mfma_f32_16x16x32_bf16(ah, b0l, acc0, 0, 0, 0);
    acc0 = __builtin_amdgcn_mfma_f32_16x16x32_bf16(al, b0h, acc0, 0, 0, 0);
    acc0 = __builtin_amdgcn_mfma_f32_16x16x32_bf16(ah, b0h, acc0, 0, 0, 0);
    acc1 = __builtin_amdgcn_mfma_f32_16x16x32_bf16(ah, b1l, acc1, 0, 0, 0);
    acc1 = __builtin_amdgcn_mfma_f32_16x16x32_bf16(al, b1h, acc1, 0, 0, 0);
    acc1 = __builtin_amdgcn_mfma_f32_16x16x32_bf16(ah, b1h, acc1, 0, 0, 0);
  }
#pragma unroll
  for (int r = 0; r < 4; ++r) {
    pA[w][(lane >> 4) * 4 + r][lane & 15] = acc0[r];
    pG[w][(lane >> 4) * 4 + r][lane & 15] = acc1[r];
  }
  __syncthreads();
  int bi = tid >> 4, ji = tid & 15;
  int b = mg * 16 + bi, j = blk * 16 + ji;
  float gsum = pA[0][bi][ji] + pA[1][bi][ji] + pA[2][bi][ji] + pA[3][bi][ji];
  float isum = pG[0][bi][0] + pG[1][bi][0] + pG[2][bi][0] + pG[3][bi][0];
  float osum = pG[0][bi][1] + pG[1][bi][1] + pG[2][bi][1] + pG[3][bi][1];
  long base = ((long)b * S_ + t) * DH_ + j;
  float gpre = hseq[base] + gsum;                       // xmc + h@Umc
  float ipre = xig[((long)b * S_ + t) * NB_ + blk] + isum;
  float opre = xog[((long)b * S_ + t) * NB_ + blk] + osum;
  float ig = 1.f / (1.f + __expf(-ipre));
  float og = 1.f / (1.f + __expf(-opre));
  float g  = tanhf(gpre);
  float cprev = (t == 0) ? c0[j] : cseq[base - DH_];
  float cn = cprev + ig * g;
  float hv = og * tanhf(cn);
  cseq[base] = cn;
  hseq[base] = hv;                                      // overwrite xmc slot
  long ho = (long)b * DH_ + j;
  unsigned short hh, hl; splitf(hv, hh, hl);
  hoh[ho] = hh; hol[ho] = hl;
}

// ---------------------------------------------------------------------------
extern "C" void kernel_launch(void* const* d_in, const int* in_sizes, int n_in,
                              void* d_out, int out_size, void* d_ws, size_t ws_size,
                              hipStream_t stream) {
  const float* x   = (const float*)d_in[0];
  const float* h0  = (const float*)d_in[1];
  const float* c0  = (const float*)d_in[2];
  const float* Wig = (const float*)d_in[3];
  const float* Uig = (const float*)d_in[4];
  const float* big = (const float*)d_in[5];
  const float* Wog = (const float*)d_in[6];
  const float* Uog = (const float*)d_in[7];
  const float* bog = (const float*)d_in[8];
  const float* Wmc = (const float*)d_in[9];
  const float* Umc = (const float*)d_in[10];
  const float* bmc = (const float*)d_in[11];

  char* ws = (char*)d_ws;
  size_t off = 0;
  auto alloc = [&](size_t bytes) { void* p = ws + off; off += (bytes + 255) & ~255UL; return p; };
  unsigned short* WmcTh = (unsigned short*)alloc(1024L * 512 * 2);
  unsigned short* WmcTl = (unsigned short*)alloc(1024L * 512 * 2);
  unsigned short* WigTh = (unsigned short*)alloc(64L * 512 * 2);
  unsigned short* WigTl = (unsigned short*)alloc(64L * 512 * 2);
  unsigned short* WogTh = (unsigned short*)alloc(64L * 512 * 2);
  unsigned short* WogTl = (unsigned short*)alloc(64L * 512 * 2);
  unsigned short* UmcTh = (unsigned short*)alloc(1024L * 1024 * 2);
  unsigned short* UmcTl = (unsigned short*)alloc(1024L * 1024 * 2);
  unsigned short* UigTh = (unsigned short*)alloc(64L * 1024 * 2);
  unsigned short* UigTl = (unsigned short*)alloc(64L * 1024 * 2);
  unsigned short* UogTh = (unsigned short*)alloc(64L * 1024 * 2);
  unsigned short* UogTl = (unsigned short*)alloc(64L * 1024 * 2);
  unsigned short* hAh   = (unsigned short*)alloc(64L * 1024 * 2);
  unsigned short* hAl   = (unsigned short*)alloc(64L * 1024 * 2);
  unsigned short* hBh   = (unsigned short*)alloc(64L * 1024 * 2);
  unsigned short* hBl   = (unsigned short*)alloc(64L * 1024 * 2);
  float* xig            = (float*)alloc(M_ * 64 * 4);
  float* xog            = (float*)alloc(M_ * 64 * 4);

  float* hseq = (float*)d_out;
  float* cseq = hseq + M_ * DH_;

  prep_kernel<<<2048, 256, 0, stream>>>(Wmc, Wig, Wog, Umc, Uig, Uog, h0,
                                        WmcTh, WmcTl, WigTh, WigTl, WogTh, WogTl,
                                        UmcTh, UmcTl, UigTh, UigTl, UogTh, UogTl,
                                        hAh, hAl);
  // Input projections (split precision); xmc goes straight into hseq.
  gemm_split<<<dim3(256, 16), 256, 0, stream>>>(x, WmcTh, WmcTl, bmc, hseq, 1024);
  gemm_split<<<dim3(256, 1), 256, 0, stream>>>(x, WigTh, WigTl, big, xig, 64);
  gemm_split<<<dim3(256, 1), 256, 0, stream>>>(x, WogTh, WogTl, bog, xog, 64);

  for (int t = 0; t < S_; ++t) {
    const unsigned short* hih = (t & 1) ? hBh : hAh;
    const unsigned short* hil = (t & 1) ? hBl : hAl;
    unsigned short* hoh       = (t & 1) ? hAh : hBh;
    unsigned short* hol       = (t & 1) ? hAl : hBl;
    lstm_step<<<dim3(64, 4), 256, 0, stream>>>(hih, hil, hoh, hol,
                                               UmcTh, UmcTl, UigTh, UigTl,
                                               UogTh, UogTl, xig, xog, c0,
                                               hseq, cseq, t);
  }
}